// Round 9
// baseline (89.738 us; speedup 1.0000x reference)
//
#include <hip/hip_runtime.h>

// PolynomialRegression via bf16 MFMA — wave-independent, barrier-free, LDS-free.
//   y[b][o] = bias_o + sum_i x[b][i] * ( (U_o x[b])_i + W1[o][i] )
// gbuild: G (2560x256 bf16) = zero-masked upper-triangular U_o rows.
// main:   each WAVE owns 16 rows x one o and the full i-triangle:
//         A-frags packed from global x into regs (no LDS, no transpose),
//         static 36-pair (ng, kc>=ng) unrolled loop: 72 b128 G-loads + 72 MFMA,
//         in-register epilogue + 16-lane shfl reduce + direct stores.
//         No __syncthreads anywhere. 640 blocks, ~150 VGPR, 3 blocks/CU.

#define DD 256
#define NF 33153
#define TPB 256

typedef __attribute__((ext_vector_type(8))) short short8;
typedef __attribute__((ext_vector_type(4))) float floatx4;

union S8U { unsigned u[4]; short8 s; };

__device__ inline unsigned short f2bf(float f) {
    unsigned u = __builtin_bit_cast(unsigned, f);
    return (unsigned short)((u + 0x7FFFu + ((u >> 16) & 1u)) >> 16);  // RNE
}
__device__ inline unsigned pack2(float lo, float hi) {   // 2xfp32 -> bf16x2, half-up
    unsigned a = __builtin_bit_cast(unsigned, hi) + 0x8000u;
    unsigned b = __builtin_bit_cast(unsigned, lo) + 0x8000u;
    return __builtin_amdgcn_perm(a, b, 0x07060302u);
}

// --- prep: scatter W2 into dense upper-triangular G (2560x256 bf16) ---
__global__ __launch_bounds__(TPB)
void gbuild_kernel(const float* __restrict__ W, unsigned short* __restrict__ G) {
    int oi = blockIdx.x;            // o*256 + i
    int o = oi >> 8, i = oi & 255;
    int j = threadIdx.x;
    int base = o * NF + 257 + i * DD - (i * (i - 1)) / 2 - i;   // + j for j>=i
    float v = (j >= i) ? W[base + j] : 0.f;
    G[oi * DD + j] = f2bf(v);
}

// --- main ---
__global__ __launch_bounds__(TPB, 3)
void PolynomialRegression_75385265979710_kernel(const float* __restrict__ x,
                                                const float* __restrict__ W,
                                                const unsigned short* __restrict__ G,
                                                float* __restrict__ out) {
    const int tid  = threadIdx.x;
    const int lane = tid & 63, wave = tid >> 6;
    const int ln   = lane & 15, quad = lane >> 4;
    const int q8   = quad * 8;
    const int o    = blockIdx.y;
    const int rowbase = (blockIdx.x * 4 + wave) * 16;   // this wave's 16 rows

    // --- pack 8 A-frags straight from global x (fp32 -> bf16, in regs) ---
    const float* xrow = x + (rowbase + ln) * DD;
    short8 a[8];
#pragma unroll
    for (int kc = 0; kc < 8; ++kc) {
        float4 v0 = *(const float4*)(xrow + kc * 32 + q8);
        float4 v1 = *(const float4*)(xrow + kc * 32 + q8 + 4);
        S8U p;
        p.u[0] = pack2(v0.x, v0.y); p.u[1] = pack2(v0.z, v0.w);
        p.u[2] = pack2(v1.x, v1.y); p.u[3] = pack2(v1.z, v1.w);
        a[kc] = p.s;
    }

    // hoisted epilogue constants
    float w1[16];
#pragma unroll
    for (int nt = 0; nt < 16; ++nt)
        w1[nt] = W[o * NF + 1 + nt * 16 + ln];
    const float bias = W[o * NF];

    floatx4 acc[16];               // [nt]: i-tile nt covers i = nt*16 + ln
#pragma unroll
    for (int nt = 0; nt < 16; ++nt) acc[nt] = (floatx4)0.f;

    const unsigned short* Gy = G + (o * DD) * DD;   // G[o] slab (131 KB, L2-hot)

    // --- static triangle: 36 (ng, kc>=ng) pairs, fully unrolled ---
#pragma unroll
    for (int ng = 0; ng < 8; ++ng) {
#pragma unroll
        for (int kc = ng; kc < 8; ++kc) {
            const unsigned short* gb = Gy + (ng * 32 + ln) * DD + kc * 32 + q8;
            short8 b0 = *(const short8*)gb;             // i-sub 0: rows ng*32+ln
            short8 b1 = *(const short8*)(gb + 16 * DD); // i-sub 1: rows ng*32+16+ln
            acc[ng * 2]     = __builtin_amdgcn_mfma_f32_16x16x32_bf16(a[kc], b0, acc[ng * 2],     0, 0, 0);
            acc[ng * 2 + 1] = __builtin_amdgcn_mfma_f32_16x16x32_bf16(a[kc], b1, acc[ng * 2 + 1], 0, 0, 0);
        }
    }

    // --- epilogue: y[m] = bias + sum_i x_f32[m][i] * (T[m][i] + W1[o][i]) ---
#pragma unroll
    for (int r = 0; r < 4; ++r) {
        const int m = rowbase + quad * 4 + r;   // C/D: row = quad*4 + reg, col = ln
        float p = 0.f;
#pragma unroll
        for (int nt = 0; nt < 16; ++nt) {
            float xv = x[m * DD + nt * 16 + ln];
            p = fmaf(xv, acc[nt][r] + w1[nt], p);
        }
        p += __shfl_xor(p, 1);
        p += __shfl_xor(p, 2);
        p += __shfl_xor(p, 4);
        p += __shfl_xor(p, 8);
        if (ln == 0) out[m * 10 + o] = p + bias;
    }
}

extern "C" void kernel_launch(void* const* d_in, const int* in_sizes, int n_in,
                              void* d_out, int out_size, void* d_ws, size_t ws_size,
                              hipStream_t stream) {
    const float* x = (const float*)d_in[0];   // (4096, 256)
    const float* W = (const float*)d_in[1];   // (10, 33153)
    float* out = (float*)d_out;               // (4096, 10)

    unsigned short* G = (unsigned short*)d_ws;   // 1.31 MB

    gbuild_kernel<<<10 * DD, TPB, 0, stream>>>(W, G);

    dim3 grid(64, 10);   // 4 waves/block x 16 rows = 64 rows/block
    PolynomialRegression_75385265979710_kernel<<<grid, TPB, 0, stream>>>(x, W, G, out);
}

// Round 10
// 69.171 us; speedup vs baseline: 1.2973x; 1.2973x over previous
//
#include <hip/hip_runtime.h>

// PolynomialRegression via bf16 MFMA, 2 launches:
//   y[b][o] = bias_o + sum_i x[b][i] * ( (U_o x[b])_i + W1[o][i] )
// gbuild v2: G (2560x256 bf16) = zero-masked upper-triangular U_o rows,
//            8 elems/thread, b128 stores (320 blocks).
// main (R7 structure, best known): 64-row x 1-o blocks; x-tile staged
//   fp32->bf16 in LDS (1 barrier); uniform fully-unrolled 9-chunk loop
//   (balanced pairs {w,7-w} -> 72 MFMA/wave, 4 m-tiles/wave amortize B);
//   B-frags = raw b128 loads from L2-hot G; fused fp32 quadratic-form
//   epilogue, x from LDS, direct stores. launch_bounds (256,3).

#define DD 256
#define NF 33153
#define TPB 256
#define ASTRIDE 264   // bf16 elems; 528 B row stride -> 2-way LDS alias (free)

typedef __attribute__((ext_vector_type(8))) short short8;
typedef __attribute__((ext_vector_type(4))) float floatx4;
typedef __attribute__((ext_vector_type(4), aligned(4))) float float4a;

union S8U { unsigned u[4]; short8 s; };

__device__ inline unsigned pack2(float lo, float hi) {   // 2xfp32 -> bf16x2, half-up
    unsigned a = __builtin_bit_cast(unsigned, hi) + 0x8000u;
    unsigned b = __builtin_bit_cast(unsigned, lo) + 0x8000u;
    return __builtin_amdgcn_perm(a, b, 0x07060302u);
}

// --- prep v2: 8 rows/block, 8 elems/thread, vector stores ---
__global__ __launch_bounds__(TPB)
void gbuild_kernel(const float* __restrict__ W, unsigned short* __restrict__ G) {
    int oi = blockIdx.x * 8 + (threadIdx.x >> 5);   // G row: o*256 + i
    int c0 = (threadIdx.x & 31) * 8;                // col
    int o = oi >> 8, i = oi & 255;
    int base = o * NF + 257 + i * 255 - ((i * (i - 1)) >> 1);   // + j for j>=i
    float4a w0 = *(const float4a*)&W[base + c0];
    float4a w1 = *(const float4a*)&W[base + c0 + 4];
    float f[8] = {w0.x, w0.y, w0.z, w0.w, w1.x, w1.y, w1.z, w1.w};
#pragma unroll
    for (int e = 0; e < 8; ++e)
        if (c0 + e < i) f[e] = 0.f;                  // mask j<i
    S8U p;
    p.u[0] = pack2(f[0], f[1]); p.u[1] = pack2(f[2], f[3]);
    p.u[2] = pack2(f[4], f[5]); p.u[3] = pack2(f[6], f[7]);
    *(short8*)&G[oi * DD + c0] = p.s;
}

// --- main ---
__global__ __launch_bounds__(TPB, 3)
void PolynomialRegression_75385265979710_kernel(const float* __restrict__ x,
                                                const float* __restrict__ W,
                                                const unsigned short* __restrict__ G,
                                                float* __restrict__ out) {
    __shared__ __align__(16) unsigned short As[64 * ASTRIDE];  // 33792 B
    __shared__ float red[4 * 64];

    const int tid  = threadIdx.x;
    const int lane = tid & 63, wave = tid >> 6;
    const int ln   = lane & 15, quad = lane >> 4;
    const int q8   = quad * 8;
    const int rowbase = blockIdx.x * 64;
    const int o  = blockIdx.y;
    const int g1 = wave, g2 = 7 - wave;
    const int rem = 8 - wave;            // chunks in group g1

    // --- stage x-tile (64 x 256) fp32 -> bf16 into padded LDS ---
#pragma unroll
    for (int it = 0; it < 8; ++it) {
        int idx = it * 2048 + tid * 8;
        int r = idx >> 8, c = idx & 255;
        const float* src = &x[(rowbase + r) * DD + c];
        float4a v0 = *(const float4a*)src;
        float4a v1 = *(const float4a*)(src + 4);
        S8U p;
        p.u[0] = pack2(v0.x, v0.y); p.u[1] = pack2(v0.z, v0.w);
        p.u[2] = pack2(v1.x, v1.y); p.u[3] = pack2(v1.z, v1.w);
        *(short8*)&As[r * ASTRIDE + c] = p.s;
    }

    // hoisted epilogue constants (latency hides under K-loop)
    int iRow[4];
    float w1v[4];
#pragma unroll
    for (int nt = 0; nt < 4; ++nt) {
        int g = (nt < 2) ? g1 : g2;
        iRow[nt] = g * 32 + (nt & 1) * 16 + ln;
        w1v[nt]  = W[o * NF + 1 + iRow[nt]];
    }
    const float bias = W[o * NF];

    __syncthreads();

    floatx4 acc[4][4];   // [m_tile][n_tile: 0,1 = group g1; 2,3 = group g2]
#pragma unroll
    for (int mt = 0; mt < 4; ++mt)
#pragma unroll
        for (int nt = 0; nt < 4; ++nt) acc[mt][nt] = (floatx4)0.f;

    const unsigned short* Gy = G + (o * DD) * DD;   // G[o] slab (131 KB, L2-hot)

    // --- uniform 9-chunk loop, fully unrolled: t<rem -> (g1, kc=g1+t),
    //     else -> (g2, kc=g2+(t-rem)). All bounds compile-time.
#pragma unroll
    for (int t = 0; t < 9; ++t) {
        const bool first = (t < rem);                      // wave-uniform
        const int g  = first ? g1 : g2;
        const int kc = first ? (g1 + t) : (g2 + (t - rem));
        const unsigned short* gb = Gy + (g * 32 + ln) * DD + kc * 32 + q8;
        short8 b0 = *(const short8*)gb;
        short8 b1 = *(const short8*)(gb + 16 * DD);
        short8 a[4];
#pragma unroll
        for (int mt = 0; mt < 4; ++mt)
            a[mt] = *(const short8*)&As[(mt * 16 + ln) * ASTRIDE + kc * 32 + q8];
        if (first) {
#pragma unroll
            for (int mt = 0; mt < 4; ++mt) {
                acc[mt][0] = __builtin_amdgcn_mfma_f32_16x16x32_bf16(a[mt], b0, acc[mt][0], 0, 0, 0);
                acc[mt][1] = __builtin_amdgcn_mfma_f32_16x16x32_bf16(a[mt], b1, acc[mt][1], 0, 0, 0);
            }
        } else {
#pragma unroll
            for (int mt = 0; mt < 4; ++mt) {
                acc[mt][2] = __builtin_amdgcn_mfma_f32_16x16x32_bf16(a[mt], b0, acc[mt][2], 0, 0, 0);
                acc[mt][3] = __builtin_amdgcn_mfma_f32_16x16x32_bf16(a[mt], b1, acc[mt][3], 0, 0, 0);
            }
        }
    }

    // --- epilogue: y_part[m] = sum_{i in wave's set} x[m][i]*(T[m][i]+W1[o][i])
#pragma unroll
    for (int mt = 0; mt < 4; ++mt) {
#pragma unroll
        for (int r = 0; r < 4; ++r) {
            const int m = mt * 16 + quad * 4 + r;   // C/D: row=quad*4+reg, col=ln
            float p = 0.f;
#pragma unroll
            for (int nt = 0; nt < 4; ++nt) {
                unsigned u = As[m * ASTRIDE + iRow[nt]];
                float xv = __builtin_bit_cast(float, u << 16);
                p = fmaf(xv, acc[mt][nt][r] + w1v[nt], p);
            }
            p += __shfl_xor(p, 1);
            p += __shfl_xor(p, 2);
            p += __shfl_xor(p, 4);
            p += __shfl_xor(p, 8);
            if (ln == 0) red[wave * 64 + m] = p;
        }
    }
    __syncthreads();

    if (tid < 64) {
        float s = red[tid] + red[64 + tid] + red[128 + tid] + red[192 + tid]
                + bias;
        out[(rowbase + tid) * 10 + o] = s;
    }
}

extern "C" void kernel_launch(void* const* d_in, const int* in_sizes, int n_in,
                              void* d_out, int out_size, void* d_ws, size_t ws_size,
                              hipStream_t stream) {
    const float* x = (const float*)d_in[0];   // (4096, 256)
    const float* W = (const float*)d_in[1];   // (10, 33153)
    float* out = (float*)d_out;               // (4096, 10)

    unsigned short* G = (unsigned short*)d_ws;   // 1.31 MB

    gbuild_kernel<<<2560 / 8, TPB, 0, stream>>>(W, G);

    dim3 grid(4096 / 64, 10);
    PolynomialRegression_75385265979710_kernel<<<grid, TPB, 0, stream>>>(x, W, G, out);
}